// Round 1
// baseline (423.054 us; speedup 1.0000x reference)
//
#include <hip/hip_runtime.h>
#include <hip/hip_bf16.h>
#include <stdint.h>

// Problem constants
#define B_N 4
#define T_N 2048
#define D_N 1024
#define H_N 16
#define HD_N 64

typedef __bf16 bf16x8 __attribute__((ext_vector_type(8)));
typedef unsigned short u16x8 __attribute__((ext_vector_type(8)));
typedef unsigned short u16x4 __attribute__((ext_vector_type(4)));
typedef float f32x4 __attribute__((ext_vector_type(4)));

static __device__ __forceinline__ unsigned short f2bf(float f) {
    union { float f; unsigned u; } v; v.f = f;
    unsigned r = v.u + 0x7fffu + ((v.u >> 16) & 1u);   // RNE
    return (unsigned short)(r >> 16);
}
static __device__ __forceinline__ float bf2f(unsigned short s) {
    union { unsigned u; float f; } v; v.u = ((unsigned)s) << 16;
    return v.f;
}
static __device__ __forceinline__ bf16x8 as_bf(u16x8 v) {
    return __builtin_bit_cast(bf16x8, v);
}

// ---------------------------------------------------------------------------
// Kernel 1: convert x f32 -> bf16 (row-major [8192][1024])
// ---------------------------------------------------------------------------
__global__ __launch_bounds__(256) void cvt_x_kernel(const float* __restrict__ x,
                                                    unsigned short* __restrict__ xb) {
    int i = (blockIdx.x * 256 + threadIdx.x) * 8;
    f32x4 a = *(const f32x4*)(x + i);
    f32x4 b = *(const f32x4*)(x + i + 4);
    u16x8 o;
    o[0] = f2bf(a[0]); o[1] = f2bf(a[1]); o[2] = f2bf(a[2]); o[3] = f2bf(a[3]);
    o[4] = f2bf(b[0]); o[5] = f2bf(b[1]); o[6] = f2bf(b[2]); o[7] = f2bf(b[3]);
    *(u16x8*)(xb + i) = o;
}

// ---------------------------------------------------------------------------
// Kernel 2: transpose+convert weights: Wt[n][k] = (bf16) W[k][n], 1024x1024
// z selects which of the 4 matrices.
// ---------------------------------------------------------------------------
__global__ __launch_bounds__(256) void cvt_w_t_kernel(
        const float* __restrict__ w0, const float* __restrict__ w1,
        const float* __restrict__ w2, const float* __restrict__ w3,
        unsigned short* __restrict__ o0, unsigned short* __restrict__ o1,
        unsigned short* __restrict__ o2, unsigned short* __restrict__ o3) {
    __shared__ float tile[32][33];
    const float* w; unsigned short* o;
    switch (blockIdx.z) {
        case 0:  w = w0; o = o0; break;
        case 1:  w = w1; o = o1; break;
        case 2:  w = w2; o = o2; break;
        default: w = w3; o = o3; break;
    }
    int n0 = blockIdx.x * 32, k0 = blockIdx.y * 32;
    int tx = threadIdx.x & 31, ty = threadIdx.x >> 5;   // 32 x 8
    #pragma unroll
    for (int r = 0; r < 4; ++r)
        tile[ty + r * 8][tx] = w[(k0 + ty + r * 8) * 1024 + n0 + tx];
    __syncthreads();
    #pragma unroll
    for (int r = 0; r < 4; ++r)
        o[(n0 + ty + r * 8) * 1024 + k0 + tx] = f2bf(tile[tx][ty + r * 8]);
}

// ---------------------------------------------------------------------------
// Kernel 3: fused QKV GEMM.  C[8192, 3072] = xb[8192,1024] @ Wt^T  (+bias)
// Wt is [3072 n][1024 k] bf16 (wq_t, wk_t, wv_t contiguous).
// Epilogue: Q,K -> [bh][t][hd] bf16 ; V -> [bh][hd][t] bf16 (transposed).
// Tile 128x128, BK=64, 4 waves (2x2), mfma 16x16x32 bf16.
// LDS XOR granule swizzle: granule g (8 bf16) of row m stored at g^(m&7).
// ---------------------------------------------------------------------------
#define BM 128
#define BN 128
#define BK 64

__global__ __launch_bounds__(256) void qkv_gemm_kernel(
        const unsigned short* __restrict__ xb,
        const unsigned short* __restrict__ wt,
        const float* __restrict__ bq, const float* __restrict__ bk,
        const float* __restrict__ bv,
        unsigned short* __restrict__ qws, unsigned short* __restrict__ kws,
        unsigned short* __restrict__ vtws) {
    __shared__ unsigned short As[BM * BK];
    __shared__ unsigned short Bs[BN * BK];
    const int tid = threadIdx.x;
    const int lane = tid & 63, wid = tid >> 6;
    const int wr = wid >> 1, wc = wid & 1;
    const int l15 = lane & 15, lg = lane >> 4;
    const int mbase = blockIdx.y * BM;
    const int nbase = blockIdx.x * BN;      // 0..3071

    f32x4 acc[4][4] = {};

    for (int k0 = 0; k0 < 1024; k0 += BK) {
        __syncthreads();
        #pragma unroll
        for (int it = 0; it < 4; ++it) {
            int flat = it * 256 + tid;               // 0..1023
            int m = flat >> 3, g = flat & 7;
            u16x8 v = *(const u16x8*)(xb + (mbase + m) * 1024 + k0 + g * 8);
            *(u16x8*)(As + m * 64 + ((g ^ (m & 7)) << 3)) = v;
        }
        #pragma unroll
        for (int it = 0; it < 4; ++it) {
            int flat = it * 256 + tid;
            int n = flat >> 3, g = flat & 7;
            u16x8 v = *(const u16x8*)(wt + (nbase + n) * 1024 + k0 + g * 8);
            *(u16x8*)(Bs + n * 64 + ((g ^ (n & 7)) << 3)) = v;
        }
        __syncthreads();
        #pragma unroll
        for (int kk = 0; kk < 2; ++kk) {
            bf16x8 a[4], b[4];
            #pragma unroll
            for (int mi = 0; mi < 4; ++mi) {
                int m = wr * 64 + mi * 16 + l15;
                int g = (kk * 4 + lg) ^ (m & 7);
                a[mi] = as_bf(*(const u16x8*)(As + m * 64 + (g << 3)));
            }
            #pragma unroll
            for (int ni = 0; ni < 4; ++ni) {
                int n = wc * 64 + ni * 16 + l15;
                int g = (kk * 4 + lg) ^ (n & 7);
                b[ni] = as_bf(*(const u16x8*)(Bs + n * 64 + (g << 3)));
            }
            #pragma unroll
            for (int mi = 0; mi < 4; ++mi)
                #pragma unroll
                for (int ni = 0; ni < 4; ++ni)
                    acc[mi][ni] = __builtin_amdgcn_mfma_f32_16x16x32_bf16(
                        a[mi], b[ni], acc[mi][ni], 0, 0, 0);
        }
    }

    // Epilogue
    const int mat = nbase >> 10;                       // 0=q 1=k 2=v (block-uniform)
    const float* bias = (mat == 0) ? bq : (mat == 1) ? bk : bv;
    #pragma unroll
    for (int ni = 0; ni < 4; ++ni) {
        int cg = (nbase & 1023) + wc * 64 + ni * 16 + l15;   // col within matrix
        float bb = bias[cg];
        int h = cg >> 6, hd = cg & 63;
        #pragma unroll
        for (int mi = 0; mi < 4; ++mi) {
            int row = mbase + wr * 64 + mi * 16 + lg * 4;     // +r
            int bidx = row >> 11;                              // batch
            int t = row & 2047;
            if (mat == 2) {
                u16x4 pv;
                #pragma unroll
                for (int r = 0; r < 4; ++r) pv[r] = f2bf(acc[mi][ni][r] + bb);
                *(u16x4*)(vtws + ((bidx * 16 + h) * 64 + hd) * 2048 + t) = pv;
            } else {
                unsigned short* dst =
                    ((mat == 0) ? qws : kws) + ((bidx * 16 + h) * 2048 + t) * 64 + hd;
                #pragma unroll
                for (int r = 0; r < 4; ++r) dst[r * 64] = f2bf(acc[mi][ni][r] + bb);
            }
        }
    }
}

// ---------------------------------------------------------------------------
// Kernel 4: causal flash attention.
// Q,K: [bh][2048][64] bf16, Vt: [bh][64][2048] bf16 -> ctx [8192][1024] bf16.
// Block: 256 thr = 4 waves; QBLK=128 (32 q-rows/wave); KV tiles of 64.
// ---------------------------------------------------------------------------
#define QBLK 128
#define KBLK 64

__global__ __launch_bounds__(256) void attn_kernel(
        const unsigned short* __restrict__ qws,
        const unsigned short* __restrict__ kws,
        const unsigned short* __restrict__ vtws,
        unsigned short* __restrict__ ctx) {
    __shared__ unsigned short Ks[KBLK * 64];     // [kv][d] swizzled
    __shared__ unsigned short Vs[64 * KBLK];     // [d][kv] swizzled
    __shared__ unsigned short Ps[4][32 * 64];    // per-wave P, swizzled

    const int tid = threadIdx.x;
    const int lane = tid & 63, wid = tid >> 6;
    const int l15 = lane & 15, lg = lane >> 4;
    const int bh = blockIdx.y;
    const int qbase = blockIdx.x * QBLK;
    const unsigned short* qp = qws + bh * 2048 * 64;
    const unsigned short* kp = kws + bh * 2048 * 64;
    const unsigned short* vp = vtws + bh * 64 * 2048;

    // Q fragments in registers, pre-scaled by 1/sqrt(64)=0.125 (exact in bf16)
    bf16x8 qf[2][2];
    #pragma unroll
    for (int i = 0; i < 2; ++i)
        #pragma unroll
        for (int kk = 0; kk < 2; ++kk) {
            int row = qbase + wid * 32 + i * 16 + l15;
            u16x8 v = *(const u16x8*)(qp + row * 64 + kk * 32 + lg * 8);
            u16x8 o;
            #pragma unroll
            for (int e = 0; e < 8; ++e) o[e] = f2bf(bf2f(v[e]) * 0.125f);
            qf[i][kk] = as_bf(o);
        }

    f32x4 acc[2][4] = {};
    float mrow[2][4], lrow[2][4];
    #pragma unroll
    for (int i = 0; i < 2; ++i)
        #pragma unroll
        for (int r = 0; r < 4; ++r) { mrow[i][r] = -1e30f; lrow[i][r] = 0.f; }

    const int kend = qbase + QBLK;
    const int qwmin = qbase + wid * 32;
    const int qwmax = qwmin + 31;

    for (int kt = 0; kt < kend; kt += KBLK) {
        __syncthreads();
        #pragma unroll
        for (int it = 0; it < 2; ++it) {
            int flat = it * 256 + tid;           // 0..511
            int r = flat >> 3, g = flat & 7;
            u16x8 v = *(const u16x8*)(kp + (kt + r) * 64 + g * 8);
            *(u16x8*)(Ks + r * 64 + ((g ^ (r & 7)) << 3)) = v;
        }
        #pragma unroll
        for (int it = 0; it < 2; ++it) {
            int flat = it * 256 + tid;
            int d = flat >> 3, g = flat & 7;
            u16x8 v = *(const u16x8*)(vp + d * 2048 + kt + g * 8);
            *(u16x8*)(Vs + d * 64 + ((g ^ (d & 7)) << 3)) = v;
        }
        __syncthreads();
        if (kt > qwmax) continue;                // fully-masked tile for this wave

        // S = Q @ K^T  (16x16 tiles: i q-frag x j k-frag)
        f32x4 s[2][4];
        #pragma unroll
        for (int j = 0; j < 4; ++j) {
            bf16x8 kf[2];
            #pragma unroll
            for (int kk = 0; kk < 2; ++kk) {
                int r = j * 16 + l15;
                int g = (kk * 4 + lg) ^ (r & 7);
                kf[kk] = as_bf(*(const u16x8*)(Ks + r * 64 + (g << 3)));
            }
            #pragma unroll
            for (int i = 0; i < 2; ++i) {
                f32x4 t = {};
                t = __builtin_amdgcn_mfma_f32_16x16x32_bf16(qf[i][0], kf[0], t, 0, 0, 0);
                t = __builtin_amdgcn_mfma_f32_16x16x32_bf16(qf[i][1], kf[1], t, 0, 0, 0);
                s[i][j] = t;
            }
        }

        // causal mask (only tiles crossing the diagonal)
        if (kt + KBLK - 1 > qwmin) {
            #pragma unroll
            for (int i = 0; i < 2; ++i)
                #pragma unroll
                for (int j = 0; j < 4; ++j)
                    #pragma unroll
                    for (int r = 0; r < 4; ++r) {
                        int qg = qwmin + i * 16 + lg * 4 + r;
                        int kg = kt + j * 16 + l15;
                        if (kg > qg) s[i][j][r] = -1e30f;
                    }
        }

        // online softmax per (i, r); rows replicated across the 16-lane group
        #pragma unroll
        for (int i = 0; i < 2; ++i) {
            #pragma unroll
            for (int r = 0; r < 4; ++r) {
                float mx = fmaxf(fmaxf(s[i][0][r], s[i][1][r]),
                                 fmaxf(s[i][2][r], s[i][3][r]));
                #pragma unroll
                for (int d = 1; d < 16; d <<= 1) mx = fmaxf(mx, __shfl_xor(mx, d));
                float mnew = fmaxf(mrow[i][r], mx);
                float alpha = __expf(mrow[i][r] - mnew);
                mrow[i][r] = mnew;
                float sum = 0.f;
                #pragma unroll
                for (int j = 0; j < 4; ++j) {
                    float p = __expf(s[i][j][r] - mnew);
                    s[i][j][r] = p;
                    sum += p;
                }
                #pragma unroll
                for (int d = 1; d < 16; d <<= 1) sum += __shfl_xor(sum, d);
                lrow[i][r] = lrow[i][r] * alpha + sum;
                #pragma unroll
                for (int jd = 0; jd < 4; ++jd) acc[i][jd][r] *= alpha;
            }
        }

        // P -> LDS (bf16, swizzled), wave-private
        unsigned short* pw = &Ps[wid][0];
        #pragma unroll
        for (int i = 0; i < 2; ++i)
            #pragma unroll
            for (int j = 0; j < 4; ++j)
                #pragma unroll
                for (int r = 0; r < 4; ++r) {
                    int prow = i * 16 + lg * 4 + r;
                    int pcol = j * 16 + l15;
                    int g = pcol >> 3, e = pcol & 7;
                    pw[prow * 64 + ((g ^ (prow & 7)) << 3) + e] = f2bf(s[i][j][r]);
                }

        // O += P @ V
        #pragma unroll
        for (int kk = 0; kk < 2; ++kk) {
            bf16x8 pa[2];
            #pragma unroll
            for (int i = 0; i < 2; ++i) {
                int prow = i * 16 + l15;
                int g = (kk * 4 + lg) ^ (prow & 7);
                pa[i] = as_bf(*(const u16x8*)(pw + prow * 64 + (g << 3)));
            }
            #pragma unroll
            for (int jd = 0; jd < 4; ++jd) {
                int vrow = jd * 16 + l15;
                int g = (kk * 4 + lg) ^ (vrow & 7);
                bf16x8 vf = as_bf(*(const u16x8*)(Vs + vrow * 64 + (g << 3)));
                #pragma unroll
                for (int i = 0; i < 2; ++i)
                    acc[i][jd] = __builtin_amdgcn_mfma_f32_16x16x32_bf16(
                        pa[i], vf, acc[i][jd], 0, 0, 0);
            }
        }
    }

    // epilogue: normalize and write ctx [b*2048+t][h*64+d] bf16
    const int bidx = bh >> 4, h = bh & 15;
    #pragma unroll
    for (int i = 0; i < 2; ++i) {
        int trow = qbase + wid * 32 + i * 16 + lg * 4;
        #pragma unroll
        for (int jd = 0; jd < 4; ++jd) {
            int col = h * 64 + jd * 16 + l15;
            #pragma unroll
            for (int r = 0; r < 4; ++r) {
                float o = acc[i][jd][r] / lrow[i][r];
                ctx[(bidx * 2048 + trow + r) * 1024 + col] = f2bf(o);
            }
        }
    }
}

// ---------------------------------------------------------------------------
// Kernel 5: output GEMM. out[8192,1024] f32 = ctx[8192,1024] @ Wo + bo
// Wo_t is [1024 n][1024 k] bf16.
// ---------------------------------------------------------------------------
__global__ __launch_bounds__(256) void out_gemm_kernel(
        const unsigned short* __restrict__ ctx,
        const unsigned short* __restrict__ wot,
        const float* __restrict__ bo,
        float* __restrict__ out) {
    __shared__ unsigned short As[BM * BK];
    __shared__ unsigned short Bs[BN * BK];
    const int tid = threadIdx.x;
    const int lane = tid & 63, wid = tid >> 6;
    const int wr = wid >> 1, wc = wid & 1;
    const int l15 = lane & 15, lg = lane >> 4;
    const int mbase = blockIdx.y * BM;
    const int nbase = blockIdx.x * BN;

    f32x4 acc[4][4] = {};

    for (int k0 = 0; k0 < 1024; k0 += BK) {
        __syncthreads();
        #pragma unroll
        for (int it = 0; it < 4; ++it) {
            int flat = it * 256 + tid;
            int m = flat >> 3, g = flat & 7;
            u16x8 v = *(const u16x8*)(ctx + (mbase + m) * 1024 + k0 + g * 8);
            *(u16x8*)(As + m * 64 + ((g ^ (m & 7)) << 3)) = v;
        }
        #pragma unroll
        for (int it = 0; it < 4; ++it) {
            int flat = it * 256 + tid;
            int n = flat >> 3, g = flat & 7;
            u16x8 v = *(const u16x8*)(wot + (nbase + n) * 1024 + k0 + g * 8);
            *(u16x8*)(Bs + n * 64 + ((g ^ (n & 7)) << 3)) = v;
        }
        __syncthreads();
        #pragma unroll
        for (int kk = 0; kk < 2; ++kk) {
            bf16x8 a[4], b[4];
            #pragma unroll
            for (int mi = 0; mi < 4; ++mi) {
                int m = wr * 64 + mi * 16 + l15;
                int g = (kk * 4 + lg) ^ (m & 7);
                a[mi] = as_bf(*(const u16x8*)(As + m * 64 + (g << 3)));
            }
            #pragma unroll
            for (int ni = 0; ni < 4; ++ni) {
                int n = wc * 64 + ni * 16 + l15;
                int g = (kk * 4 + lg) ^ (n & 7);
                b[ni] = as_bf(*(const u16x8*)(Bs + n * 64 + (g << 3)));
            }
            #pragma unroll
            for (int mi = 0; mi < 4; ++mi)
                #pragma unroll
                for (int ni = 0; ni < 4; ++ni)
                    acc[mi][ni] = __builtin_amdgcn_mfma_f32_16x16x32_bf16(
                        a[mi], b[ni], acc[mi][ni], 0, 0, 0);
        }
    }

    #pragma unroll
    for (int ni = 0; ni < 4; ++ni) {
        int ncol = nbase + wc * 64 + ni * 16 + l15;
        float bb = bo[ncol];
        #pragma unroll
        for (int mi = 0; mi < 4; ++mi) {
            int row = mbase + wr * 64 + mi * 16 + lg * 4;
            #pragma unroll
            for (int r = 0; r < 4; ++r)
                out[(row + r) * 1024 + ncol] = acc[mi][ni][r] + bb;
        }
    }
}

// ---------------------------------------------------------------------------
extern "C" void kernel_launch(void* const* d_in, const int* in_sizes, int n_in,
                              void* d_out, int out_size, void* d_ws, size_t ws_size,
                              hipStream_t stream) {
    const float* x  = (const float*)d_in[0];
    const float* wq = (const float*)d_in[1];
    const float* bq = (const float*)d_in[2];
    const float* wk = (const float*)d_in[3];
    const float* bk = (const float*)d_in[4];
    const float* wv = (const float*)d_in[5];
    const float* bv = (const float*)d_in[6];
    const float* wo = (const float*)d_in[7];
    const float* bo = (const float*)d_in[8];
    float* out = (float*)d_out;

    char* ws = (char*)d_ws;
    unsigned short* xb   = (unsigned short*)(ws);                         // 16 MB
    unsigned short* wqt  = (unsigned short*)(ws + (16u << 20));           // 2 MB
    unsigned short* wkt  = (unsigned short*)(ws + (18u << 20));           // 2 MB
    unsigned short* wvt  = (unsigned short*)(ws + (20u << 20));           // 2 MB
    unsigned short* wot  = (unsigned short*)(ws + (22u << 20));           // 2 MB
    unsigned short* qws  = (unsigned short*)(ws + (24u << 20));           // 16 MB
    unsigned short* kws  = (unsigned short*)(ws + (40u << 20));           // 16 MB
    unsigned short* vtws = (unsigned short*)(ws + (56u << 20));           // 16 MB
    unsigned short* ctx  = (unsigned short*)(ws + (72u << 20));           // 16 MB

    cvt_x_kernel<<<4096, 256, 0, stream>>>(x, xb);
    cvt_w_t_kernel<<<dim3(32, 32, 4), 256, 0, stream>>>(wq, wk, wv, wo,
                                                        wqt, wkt, wvt, wot);
    qkv_gemm_kernel<<<dim3(24, 64), 256, 0, stream>>>(xb, wqt, bq, bk, bv,
                                                      qws, kws, vtws);
    attn_kernel<<<dim3(16, 64), 256, 0, stream>>>(qws, kws, vtws, ctx);
    out_gemm_kernel<<<dim3(8, 64), 256, 0, stream>>>(ctx, wot, bo, out);
}

// Round 2
// 258.201 us; speedup vs baseline: 1.6385x; 1.6385x over previous
//
#include <hip/hip_runtime.h>
#include <hip/hip_bf16.h>
#include <stdint.h>

// Problem constants
#define B_N 4
#define T_N 2048
#define D_N 1024
#define H_N 16
#define HD_N 64

typedef __bf16 bf16x8 __attribute__((ext_vector_type(8)));
typedef unsigned short u16x8 __attribute__((ext_vector_type(8)));
typedef unsigned short u16x4 __attribute__((ext_vector_type(4)));
typedef float f32x4 __attribute__((ext_vector_type(4)));
typedef float f32x16 __attribute__((ext_vector_type(16)));

static __device__ __forceinline__ unsigned short f2bf(float f) {
    union { float f; unsigned u; } v; v.f = f;
    unsigned r = v.u + 0x7fffu + ((v.u >> 16) & 1u);   // RNE
    return (unsigned short)(r >> 16);
}
static __device__ __forceinline__ float bf2f(unsigned short s) {
    union { unsigned u; float f; } v; v.u = ((unsigned)s) << 16;
    return v.f;
}
static __device__ __forceinline__ bf16x8 as_bf(u16x8 v) {
    return __builtin_bit_cast(bf16x8, v);
}
// truncating pack of two f32 -> two bf16 in one u32 (low = a)
static __device__ __forceinline__ unsigned packbf(float a, float b) {
    union { float f; unsigned u; } x, y; x.f = a; y.f = b;
    return (x.u >> 16) | (y.u & 0xffff0000u);
}

// ---------------------------------------------------------------------------
// Kernel 1: convert x f32 -> bf16 (row-major [8192][1024])
// ---------------------------------------------------------------------------
__global__ __launch_bounds__(256) void cvt_x_kernel(const float* __restrict__ x,
                                                    unsigned short* __restrict__ xb) {
    int i = (blockIdx.x * 256 + threadIdx.x) * 8;
    f32x4 a = *(const f32x4*)(x + i);
    f32x4 b = *(const f32x4*)(x + i + 4);
    u16x8 o;
    o[0] = f2bf(a[0]); o[1] = f2bf(a[1]); o[2] = f2bf(a[2]); o[3] = f2bf(a[3]);
    o[4] = f2bf(b[0]); o[5] = f2bf(b[1]); o[6] = f2bf(b[2]); o[7] = f2bf(b[3]);
    *(u16x8*)(xb + i) = o;
}

// ---------------------------------------------------------------------------
// Kernel 2: transpose+convert weights: Wt[n][k] = (bf16) W[k][n], 1024x1024
// ---------------------------------------------------------------------------
__global__ __launch_bounds__(256) void cvt_w_t_kernel(
        const float* __restrict__ w0, const float* __restrict__ w1,
        const float* __restrict__ w2, const float* __restrict__ w3,
        unsigned short* __restrict__ o0, unsigned short* __restrict__ o1,
        unsigned short* __restrict__ o2, unsigned short* __restrict__ o3) {
    __shared__ float tile[32][33];
    const float* w; unsigned short* o;
    switch (blockIdx.z) {
        case 0:  w = w0; o = o0; break;
        case 1:  w = w1; o = o1; break;
        case 2:  w = w2; o = o2; break;
        default: w = w3; o = o3; break;
    }
    int n0 = blockIdx.x * 32, k0 = blockIdx.y * 32;
    int tx = threadIdx.x & 31, ty = threadIdx.x >> 5;   // 32 x 8
    #pragma unroll
    for (int r = 0; r < 4; ++r)
        tile[ty + r * 8][tx] = w[(k0 + ty + r * 8) * 1024 + n0 + tx];
    __syncthreads();
    #pragma unroll
    for (int r = 0; r < 4; ++r)
        o[(n0 + ty + r * 8) * 1024 + k0 + tx] = f2bf(tile[tx][ty + r * 8]);
}

// ---------------------------------------------------------------------------
// Kernel 3: fused QKV GEMM (128x128 tile, BK=64, 4 waves, 16x16x32 MFMA)
// Epilogue: Q,K -> [bh][t][hd] bf16 ; V -> [bh][hd][t] bf16 (transposed).
// ---------------------------------------------------------------------------
#define BM 128
#define BN 128
#define BK 64

__global__ __launch_bounds__(256) void qkv_gemm_kernel(
        const unsigned short* __restrict__ xb,
        const unsigned short* __restrict__ wt,
        const float* __restrict__ bq, const float* __restrict__ bk,
        const float* __restrict__ bv,
        unsigned short* __restrict__ qws, unsigned short* __restrict__ kws,
        unsigned short* __restrict__ vtws) {
    __shared__ unsigned short As[BM * BK];
    __shared__ unsigned short Bs[BN * BK];
    const int tid = threadIdx.x;
    const int lane = tid & 63, wid = tid >> 6;
    const int wr = wid >> 1, wc = wid & 1;
    const int l15 = lane & 15, lg = lane >> 4;
    const int mbase = blockIdx.y * BM;
    const int nbase = blockIdx.x * BN;      // 0..3071

    f32x4 acc[4][4] = {};

    for (int k0 = 0; k0 < 1024; k0 += BK) {
        __syncthreads();
        #pragma unroll
        for (int it = 0; it < 4; ++it) {
            int flat = it * 256 + tid;               // 0..1023
            int m = flat >> 3, g = flat & 7;
            u16x8 v = *(const u16x8*)(xb + (mbase + m) * 1024 + k0 + g * 8);
            *(u16x8*)(As + m * 64 + ((g ^ (m & 7)) << 3)) = v;
        }
        #pragma unroll
        for (int it = 0; it < 4; ++it) {
            int flat = it * 256 + tid;
            int n = flat >> 3, g = flat & 7;
            u16x8 v = *(const u16x8*)(wt + (nbase + n) * 1024 + k0 + g * 8);
            *(u16x8*)(Bs + n * 64 + ((g ^ (n & 7)) << 3)) = v;
        }
        __syncthreads();
        #pragma unroll
        for (int kk = 0; kk < 2; ++kk) {
            bf16x8 a[4], b[4];
            #pragma unroll
            for (int mi = 0; mi < 4; ++mi) {
                int m = wr * 64 + mi * 16 + l15;
                int g = (kk * 4 + lg) ^ (m & 7);
                a[mi] = as_bf(*(const u16x8*)(As + m * 64 + (g << 3)));
            }
            #pragma unroll
            for (int ni = 0; ni < 4; ++ni) {
                int n = wc * 64 + ni * 16 + l15;
                int g = (kk * 4 + lg) ^ (n & 7);
                b[ni] = as_bf(*(const u16x8*)(Bs + n * 64 + (g << 3)));
            }
            #pragma unroll
            for (int mi = 0; mi < 4; ++mi)
                #pragma unroll
                for (int ni = 0; ni < 4; ++ni)
                    acc[mi][ni] = __builtin_amdgcn_mfma_f32_16x16x32_bf16(
                        a[mi], b[ni], acc[mi][ni], 0, 0, 0);
        }
    }

    // Epilogue
    const int mat = nbase >> 10;                       // 0=q 1=k 2=v (block-uniform)
    const float* bias = (mat == 0) ? bq : (mat == 1) ? bk : bv;
    #pragma unroll
    for (int ni = 0; ni < 4; ++ni) {
        int cg = (nbase & 1023) + wc * 64 + ni * 16 + l15;   // col within matrix
        float bb = bias[cg];
        int h = cg >> 6, hd = cg & 63;
        #pragma unroll
        for (int mi = 0; mi < 4; ++mi) {
            int row = mbase + wr * 64 + mi * 16 + lg * 4;     // +r
            int bidx = row >> 11;                              // batch
            int t = row & 2047;
            if (mat == 2) {
                u16x4 pv;
                #pragma unroll
                for (int r = 0; r < 4; ++r) pv[r] = f2bf(acc[mi][ni][r] + bb);
                *(u16x4*)(vtws + ((bidx * 16 + h) * 64 + hd) * 2048 + t) = pv;
            } else {
                unsigned short* dst =
                    ((mat == 0) ? qws : kws) + ((bidx * 16 + h) * 2048 + t) * 64 + hd;
                #pragma unroll
                for (int r = 0; r < 4; ++r) dst[r * 64] = f2bf(acc[mi][ni][r] + bb);
            }
        }
    }
}

// ---------------------------------------------------------------------------
// Kernel 4: causal flash attention — swapped-operand 32x32 structure.
// Q,K: [bh][2048][64] bf16, Vt: [bh][64][2048] bf16 -> ctx [8192][1024] bf16.
// 4 waves x 32 q-rows (QBLK=128); KV tiles of 64, double-buffered LDS.
// S^T = mfma(K, Q): lane&31 = q column -> P row lane-local (pair l, l+32).
// PV: O^T = mfma(V^T, P^T). Softmax fully in-register (exp2 domain).
// Grid: 1024 blocks, LPT order (heavy qb first).
// ---------------------------------------------------------------------------
#define AQB 128
#define AKV 64

__global__ __launch_bounds__(256, 3) void attn_kernel(
        const unsigned short* __restrict__ qws,
        const unsigned short* __restrict__ kws,
        const unsigned short* __restrict__ vtws,
        unsigned short* __restrict__ ctx) {
    __shared__ unsigned short Ks[2][AKV * 64];   // [kv][d] swizzled, dbuf
    __shared__ unsigned short Vs[2][64 * AKV];   // [d][kv] swizzled, dbuf
    __shared__ unsigned short Os[4][32 * 64];    // per-wave O transpose buffer

    const int tid = threadIdx.x;
    const int lane = tid & 63, wid = tid >> 6;
    const int l31 = lane & 31, hi = lane >> 5;
    const int qb = 15 - (int)(blockIdx.x >> 6);   // LPT: heavy blocks first
    const int bh = blockIdx.x & 63;
    const int qbase = qb * AQB;
    const int qwbase = qbase + wid * 32;
    const unsigned short* qp = qws + bh * 2048 * 64;
    const unsigned short* kp = kws + bh * 2048 * 64;
    const unsigned short* vp = vtws + bh * 64 * 2048;

    // Q as B-operand frags; fold 1/sqrt(64) * log2(e) (exp2-domain softmax)
    const float QSCALE = 0.125f * 1.44269504f;
    bf16x8 qf[4];
    #pragma unroll
    for (int ks = 0; ks < 4; ++ks) {
        u16x8 v = *(const u16x8*)(qp + (qwbase + l31) * 64 + ks * 16 + hi * 8);
        u16x8 o;
        #pragma unroll
        for (int e = 0; e < 8; ++e) o[e] = f2bf(bf2f(v[e]) * QSCALE);
        qf[ks] = as_bf(o);
    }

    f32x16 acc0 = {}, acc1 = {};
    float m_run = -1e30f, lsum = 0.f;

    const int nt = 2 * qb + 2;                    // KV tiles for this block
    const int wnt = 2 * qb + 1 + (wid >> 1);      // tiles this wave computes

    u16x8 kr[2], vr[2];
    // prologue: stage tile 0 into buffer 0
    #pragma unroll
    for (int it = 0; it < 2; ++it) {
        int flat = it * 256 + tid, r = flat >> 3, g = flat & 7;
        kr[it] = *(const u16x8*)(kp + r * 64 + g * 8);
        vr[it] = *(const u16x8*)(vp + r * 2048 + g * 8);
    }
    #pragma unroll
    for (int it = 0; it < 2; ++it) {
        int flat = it * 256 + tid, r = flat >> 3, g = flat & 7;
        *(u16x8*)(&Ks[0][r * 64 + ((g ^ (r & 7)) << 3)]) = kr[it];
        *(u16x8*)(&Vs[0][r * 64 + ((g ^ (r & 7)) << 3)]) = vr[it];
    }
    __syncthreads();

    for (int t = 0; t < nt; ++t) {
        const int cur = t & 1;
        const int kt = t * AKV;
        // T14: issue next tile's global loads before compute
        if (t + 1 < nt) {
            int kt2 = kt + AKV;
            #pragma unroll
            for (int it = 0; it < 2; ++it) {
                int flat = it * 256 + tid, r = flat >> 3, g = flat & 7;
                kr[it] = *(const u16x8*)(kp + (kt2 + r) * 64 + g * 8);
                vr[it] = *(const u16x8*)(vp + r * 2048 + kt2 + g * 8);
            }
        }
        if (t < wnt) {
            const unsigned short* kb = &Ks[cur][0];
            const unsigned short* vb = &Vs[cur][0];
            #pragma unroll
            for (int half = 0; half < 2; ++half) {
                const int kvbase = kt + half * 32;
                if (kvbase > qwbase + 31) continue;          // fully masked
                // S^T = K @ Q  (32 kv x 32 q), 4 k-steps over d=64
                f32x16 st = {};
                #pragma unroll
                for (int ks = 0; ks < 4; ++ks) {
                    int row = half * 32 + l31;
                    int g = (ks * 2 + hi) ^ (row & 7);
                    bf16x8 kf = as_bf(*(const u16x8*)(kb + row * 64 + (g << 3)));
                    st = __builtin_amdgcn_mfma_f32_32x32x16_bf16(kf, qf[ks], st, 0, 0, 0);
                }
                // causal mask (diagonal tiles only)
                if (kvbase + 31 > qwbase) {
                    int q = qwbase + l31;
                    #pragma unroll
                    for (int r = 0; r < 16; ++r) {
                        int kv = kvbase + (r & 3) + 8 * (r >> 2) + 4 * hi;
                        if (kv > q) st[r] = -1e30f;
                    }
                }
                // row max: 15 fmax + one cross-half exchange
                float pmax = st[0];
                #pragma unroll
                for (int r = 1; r < 16; ++r) pmax = fmaxf(pmax, st[r]);
                pmax = fmaxf(pmax, __shfl_xor(pmax, 32));
                // defer-max (T13): rescale only when max grows > 11.5 (log2)
                if (!__all(pmax - m_run <= 11.5f)) {
                    float mnew = fmaxf(m_run, pmax);
                    float alpha = __builtin_amdgcn_exp2f(m_run - mnew);
                    m_run = mnew;
                    lsum *= alpha;
                    #pragma unroll
                    for (int r = 0; r < 16; ++r) { acc0[r] *= alpha; acc1[r] *= alpha; }
                }
                float p[16];
                float ls = 0.f;
                #pragma unroll
                for (int r = 0; r < 16; ++r) {
                    p[r] = __builtin_amdgcn_exp2f(st[r] - m_run);
                    ls += p[r];
                }
                lsum += ls;
                // P -> bf16 B-frags in-register (pack + cross-half shfl)
                unsigned c[8], x[8];
                #pragma unroll
                for (int i = 0; i < 8; ++i) c[i] = packbf(p[2 * i], p[2 * i + 1]);
                #pragma unroll
                for (int i = 0; i < 8; ++i) x[i] = (unsigned)__shfl_xor((int)c[i], 32);
                union { u16x8 v; unsigned w[4]; } pb0, pb1;
                pb0.w[0] = hi ? x[2] : c[0];
                pb0.w[1] = hi ? x[3] : c[1];
                pb0.w[2] = hi ? c[2] : x[0];
                pb0.w[3] = hi ? c[3] : x[1];
                pb1.w[0] = hi ? x[6] : c[4];
                pb1.w[1] = hi ? x[7] : c[5];
                pb1.w[2] = hi ? c[6] : x[4];
                pb1.w[3] = hi ? c[7] : x[5];
                // O^T += V^T @ P^T   (2 d-blocks x 2 k-steps)
                #pragma unroll
                for (int db = 0; db < 2; ++db) {
                    f32x16& accd = db ? acc1 : acc0;
                    #pragma unroll
                    for (int ks2 = 0; ks2 < 2; ++ks2) {
                        int row = db * 32 + l31;
                        int g = (half * 4 + ks2 * 2 + hi) ^ (row & 7);
                        bf16x8 vf = as_bf(*(const u16x8*)(vb + row * 64 + (g << 3)));
                        accd = __builtin_amdgcn_mfma_f32_32x32x16_bf16(
                            vf, ks2 ? pb1.v : pb0.v, accd, 0, 0, 0);
                    }
                }
            }
        }
        __syncthreads();
        if (t + 1 < nt) {
            unsigned short* dk = &Ks[cur ^ 1][0];
            unsigned short* dv = &Vs[cur ^ 1][0];
            #pragma unroll
            for (int it = 0; it < 2; ++it) {
                int flat = it * 256 + tid, r = flat >> 3, g = flat & 7;
                *(u16x8*)(dk + r * 64 + ((g ^ (r & 7)) << 3)) = kr[it];
                *(u16x8*)(dv + r * 64 + ((g ^ (r & 7)) << 3)) = vr[it];
            }
        }
        __syncthreads();
    }

    // epilogue: combine halves, normalize, transpose via LDS, coalesced store
    lsum += __shfl_xor(lsum, 32);
    float rinv = __builtin_amdgcn_rcpf(lsum);
    unsigned short* ow = &Os[wid][0];
    #pragma unroll
    for (int db = 0; db < 2; ++db) {
        const f32x16& accd = db ? acc1 : acc0;
        #pragma unroll
        for (int r = 0; r < 16; r += 2) {
            int d = db * 32 + (r & 3) + 8 * (r >> 2) + 4 * hi;
            unsigned w = packbf(accd[r] * rinv, accd[r + 1] * rinv);
            int g = (d >> 3) ^ (l31 & 7);
            *(unsigned*)(ow + l31 * 64 + (g << 3) + (d & 7)) = w;
        }
    }
    __syncthreads();
    const int bidx = bh >> 4, h = bh & 15;
    #pragma unroll
    for (int rr = 0; rr < 4; ++rr) {
        int flat = rr * 64 + lane;                 // 0..255
        int q = flat >> 3, g = flat & 7;
        u16x8 v = *(const u16x8*)(ow + q * 64 + ((g ^ (q & 7)) << 3));
        int qg = qbase + wid * 32 + q;
        *(u16x8*)(ctx + (bidx * 2048 + qg) * 1024 + h * 64 + g * 8) = v;
    }
}

// ---------------------------------------------------------------------------
// Kernel 5: output GEMM. out[8192,1024] f32 = ctx[8192,1024] @ Wo + bo
// ---------------------------------------------------------------------------
__global__ __launch_bounds__(256) void out_gemm_kernel(
        const unsigned short* __restrict__ ctx,
        const unsigned short* __restrict__ wot,
        const float* __restrict__ bo,
        float* __restrict__ out) {
    __shared__ unsigned short As[BM * BK];
    __shared__ unsigned short Bs[BN * BK];
    const int tid = threadIdx.x;
    const int lane = tid & 63, wid = tid >> 6;
    const int wr = wid >> 1, wc = wid & 1;
    const int l15 = lane & 15, lg = lane >> 4;
    const int mbase = blockIdx.y * BM;
    const int nbase = blockIdx.x * BN;

    f32x4 acc[4][4] = {};

    for (int k0 = 0; k0 < 1024; k0 += BK) {
        __syncthreads();
        #pragma unroll
        for (int it = 0; it < 4; ++it) {
            int flat = it * 256 + tid;
            int m = flat >> 3, g = flat & 7;
            u16x8 v = *(const u16x8*)(ctx + (mbase + m) * 1024 + k0 + g * 8);
            *(u16x8*)(As + m * 64 + ((g ^ (m & 7)) << 3)) = v;
        }
        #pragma unroll
        for (int it = 0; it < 4; ++it) {
            int flat = it * 256 + tid;
            int n = flat >> 3, g = flat & 7;
            u16x8 v = *(const u16x8*)(wot + (nbase + n) * 1024 + k0 + g * 8);
            *(u16x8*)(Bs + n * 64 + ((g ^ (n & 7)) << 3)) = v;
        }
        __syncthreads();
        #pragma unroll
        for (int kk = 0; kk < 2; ++kk) {
            bf16x8 a[4], b[4];
            #pragma unroll
            for (int mi = 0; mi < 4; ++mi) {
                int m = wr * 64 + mi * 16 + l15;
                int g = (kk * 4 + lg) ^ (m & 7);
                a[mi] = as_bf(*(const u16x8*)(As + m * 64 + (g << 3)));
            }
            #pragma unroll
            for (int ni = 0; ni < 4; ++ni) {
                int n = wc * 64 + ni * 16 + l15;
                int g = (kk * 4 + lg) ^ (n & 7);
                b[ni] = as_bf(*(const u16x8*)(Bs + n * 64 + (g << 3)));
            }
            #pragma unroll
            for (int mi = 0; mi < 4; ++mi)
                #pragma unroll
                for (int ni = 0; ni < 4; ++ni)
                    acc[mi][ni] = __builtin_amdgcn_mfma_f32_16x16x32_bf16(
                        a[mi], b[ni], acc[mi][ni], 0, 0, 0);
        }
    }

    #pragma unroll
    for (int ni = 0; ni < 4; ++ni) {
        int ncol = nbase + wc * 64 + ni * 16 + l15;
        float bb = bo[ncol];
        #pragma unroll
        for (int mi = 0; mi < 4; ++mi) {
            int row = mbase + wr * 64 + mi * 16 + lg * 4;
            #pragma unroll
            for (int r = 0; r < 4; ++r)
                out[(row + r) * 1024 + ncol] = acc[mi][ni][r] + bb;
        }
    }
}

// ---------------------------------------------------------------------------
extern "C" void kernel_launch(void* const* d_in, const int* in_sizes, int n_in,
                              void* d_out, int out_size, void* d_ws, size_t ws_size,
                              hipStream_t stream) {
    const float* x  = (const float*)d_in[0];
    const float* wq = (const float*)d_in[1];
    const float* bq = (const float*)d_in[2];
    const float* wk = (const float*)d_in[3];
    const float* bk = (const float*)d_in[4];
    const float* wv = (const float*)d_in[5];
    const float* bv = (const float*)d_in[6];
    const float* wo = (const float*)d_in[7];
    const float* bo = (const float*)d_in[8];
    float* out = (float*)d_out;

    char* ws = (char*)d_ws;
    unsigned short* xb   = (unsigned short*)(ws);                         // 16 MB
    unsigned short* wqt  = (unsigned short*)(ws + (16u << 20));           // 2 MB
    unsigned short* wkt  = (unsigned short*)(ws + (18u << 20));           // 2 MB
    unsigned short* wvt  = (unsigned short*)(ws + (20u << 20));           // 2 MB
    unsigned short* wot  = (unsigned short*)(ws + (22u << 20));           // 2 MB
    unsigned short* qws  = (unsigned short*)(ws + (24u << 20));           // 16 MB
    unsigned short* kws  = (unsigned short*)(ws + (40u << 20));           // 16 MB
    unsigned short* vtws = (unsigned short*)(ws + (56u << 20));           // 16 MB
    unsigned short* ctx  = (unsigned short*)(ws + (72u << 20));           // 16 MB

    cvt_x_kernel<<<4096, 256, 0, stream>>>(x, xb);
    cvt_w_t_kernel<<<dim3(32, 32, 4), 256, 0, stream>>>(wq, wk, wv, wo,
                                                        wqt, wkt, wvt, wot);
    qkv_gemm_kernel<<<dim3(24, 64), 256, 0, stream>>>(xb, wqt, bq, bk, bv,
                                                      qws, kws, vtws);
    attn_kernel<<<1024, 256, 0, stream>>>(qws, kws, vtws, ctx);
    out_gemm_kernel<<<dim3(8, 64), 256, 0, stream>>>(ctx, wot, bo, out);
}

// Round 3
// 250.094 us; speedup vs baseline: 1.6916x; 1.0324x over previous
//
#include <hip/hip_runtime.h>
#include <hip/hip_bf16.h>
#include <stdint.h>

// Problem constants
#define B_N 4
#define T_N 2048
#define D_N 1024
#define H_N 16
#define HD_N 64

typedef __bf16 bf16x8 __attribute__((ext_vector_type(8)));
typedef unsigned short u16x8 __attribute__((ext_vector_type(8)));
typedef unsigned short u16x4 __attribute__((ext_vector_type(4)));
typedef float f32x4 __attribute__((ext_vector_type(4)));
typedef float f32x16 __attribute__((ext_vector_type(16)));

static __device__ __forceinline__ unsigned short f2bf(float f) {
    union { float f; unsigned u; } v; v.f = f;
    unsigned r = v.u + 0x7fffu + ((v.u >> 16) & 1u);   // RNE
    return (unsigned short)(r >> 16);
}
static __device__ __forceinline__ float bf2f(unsigned short s) {
    union { unsigned u; float f; } v; v.u = ((unsigned)s) << 16;
    return v.f;
}
static __device__ __forceinline__ bf16x8 as_bf(u16x8 v) {
    return __builtin_bit_cast(bf16x8, v);
}
// truncating pack of two f32 -> two bf16 in one u32 (low = a)
static __device__ __forceinline__ unsigned packbf(float a, float b) {
    union { float f; unsigned u; } x, y; x.f = a; y.f = b;
    return (x.u >> 16) | (y.u & 0xffff0000u);
}
// async global->LDS, 16B per lane; dst is wave-uniform base, HW adds lane*16
static __device__ __forceinline__ void gload_lds16(const void* g, void* l) {
    __builtin_amdgcn_global_load_lds(
        (const __attribute__((address_space(1))) void*)g,
        (__attribute__((address_space(3))) void*)l, 16, 0, 0);
}

// ---------------------------------------------------------------------------
// Kernel 1: convert x f32 -> bf16 (row-major [8192][1024])
// ---------------------------------------------------------------------------
__global__ __launch_bounds__(256) void cvt_x_kernel(const float* __restrict__ x,
                                                    unsigned short* __restrict__ xb) {
    int i = (blockIdx.x * 256 + threadIdx.x) * 8;
    f32x4 a = *(const f32x4*)(x + i);
    f32x4 b = *(const f32x4*)(x + i + 4);
    u16x8 o;
    o[0] = f2bf(a[0]); o[1] = f2bf(a[1]); o[2] = f2bf(a[2]); o[3] = f2bf(a[3]);
    o[4] = f2bf(b[0]); o[5] = f2bf(b[1]); o[6] = f2bf(b[2]); o[7] = f2bf(b[3]);
    *(u16x8*)(xb + i) = o;
}

// ---------------------------------------------------------------------------
// Kernel 2: transpose+convert weights: Wt[n][k] = (bf16) W[k][n], 1024x1024
// ---------------------------------------------------------------------------
__global__ __launch_bounds__(256) void cvt_w_t_kernel(
        const float* __restrict__ w0, const float* __restrict__ w1,
        const float* __restrict__ w2, const float* __restrict__ w3,
        unsigned short* __restrict__ o0, unsigned short* __restrict__ o1,
        unsigned short* __restrict__ o2, unsigned short* __restrict__ o3) {
    __shared__ float tile[32][33];
    const float* w; unsigned short* o;
    switch (blockIdx.z) {
        case 0:  w = w0; o = o0; break;
        case 1:  w = w1; o = o1; break;
        case 2:  w = w2; o = o2; break;
        default: w = w3; o = o3; break;
    }
    int n0 = blockIdx.x * 32, k0 = blockIdx.y * 32;
    int tx = threadIdx.x & 31, ty = threadIdx.x >> 5;   // 32 x 8
    #pragma unroll
    for (int r = 0; r < 4; ++r)
        tile[ty + r * 8][tx] = w[(k0 + ty + r * 8) * 1024 + n0 + tx];
    __syncthreads();
    #pragma unroll
    for (int r = 0; r < 4; ++r)
        o[(n0 + ty + r * 8) * 1024 + k0 + tx] = f2bf(tile[tx][ty + r * 8]);
}

// ---------------------------------------------------------------------------
// Kernel 3: fused QKV GEMM (128x128 tile, BK=64, 4 waves, 16x16x32 MFMA)
// Staging via global_load_lds width=16: linear LDS dest, pre-swizzled source
// (rule #21). Source granule for lane l is (l&7)^(l>>3) — loop-invariant.
// Epilogue: Q,K -> [bh][t][hd] bf16 ; V -> [bh][hd][t] bf16 (transposed).
// ---------------------------------------------------------------------------
#define BM 128
#define BN 128
#define BK 64

__global__ __launch_bounds__(256) void qkv_gemm_kernel(
        const unsigned short* __restrict__ xb,
        const unsigned short* __restrict__ wt,
        const float* __restrict__ bq, const float* __restrict__ bk,
        const float* __restrict__ bv,
        unsigned short* __restrict__ qws, unsigned short* __restrict__ kws,
        unsigned short* __restrict__ vtws) {
    __shared__ unsigned short As[BM * BK];
    __shared__ unsigned short Bs[BN * BK];
    const int tid = threadIdx.x;
    const int lane = tid & 63, wid = tid >> 6;
    const int wr = wid >> 1, wc = wid & 1;
    const int l15 = lane & 15, lg = lane >> 4;
    const int mbase = blockIdx.y * BM;
    const int nbase = blockIdx.x * BN;      // 0..3071

    // staging geometry: wave w covers rows [w*32, w*32+32); issue i covers 8 rows
    const int rsub = lane >> 3;                 // row within 8-row group
    const int gsw  = (lane & 7) ^ rsub;         // pre-swizzled source granule
    const unsigned short* asrc0 = xb + (mbase + wid * 32 + rsub) * 1024 + gsw * 8;
    const unsigned short* bsrc0 = wt + (nbase + wid * 32 + rsub) * 1024 + gsw * 8;
    char* adst0 = (char*)As + wid * 4096;
    char* bdst0 = (char*)Bs + wid * 4096;

    f32x4 acc[4][4] = {};

    for (int k0 = 0; k0 < 1024; k0 += BK) {
        __syncthreads();
        #pragma unroll
        for (int i = 0; i < 4; ++i)
            gload_lds16(asrc0 + i * 8 * 1024 + k0, adst0 + i * 1024);
        #pragma unroll
        for (int i = 0; i < 4; ++i)
            gload_lds16(bsrc0 + i * 8 * 1024 + k0, bdst0 + i * 1024);
        __syncthreads();
        #pragma unroll
        for (int kk = 0; kk < 2; ++kk) {
            bf16x8 a[4], b[4];
            #pragma unroll
            for (int mi = 0; mi < 4; ++mi) {
                int m = wr * 64 + mi * 16 + l15;
                int g = (kk * 4 + lg) ^ (m & 7);
                a[mi] = as_bf(*(const u16x8*)(As + m * 64 + (g << 3)));
            }
            #pragma unroll
            for (int ni = 0; ni < 4; ++ni) {
                int n = wc * 64 + ni * 16 + l15;
                int g = (kk * 4 + lg) ^ (n & 7);
                b[ni] = as_bf(*(const u16x8*)(Bs + n * 64 + (g << 3)));
            }
            #pragma unroll
            for (int mi = 0; mi < 4; ++mi)
                #pragma unroll
                for (int ni = 0; ni < 4; ++ni)
                    acc[mi][ni] = __builtin_amdgcn_mfma_f32_16x16x32_bf16(
                        a[mi], b[ni], acc[mi][ni], 0, 0, 0);
        }
    }

    // Epilogue
    const int mat = nbase >> 10;                       // 0=q 1=k 2=v (block-uniform)
    const float* bias = (mat == 0) ? bq : (mat == 1) ? bk : bv;
    #pragma unroll
    for (int ni = 0; ni < 4; ++ni) {
        int cg = (nbase & 1023) + wc * 64 + ni * 16 + l15;   // col within matrix
        float bb = bias[cg];
        int h = cg >> 6, hd = cg & 63;
        #pragma unroll
        for (int mi = 0; mi < 4; ++mi) {
            int row = mbase + wr * 64 + mi * 16 + lg * 4;     // +r
            int bidx = row >> 11;                              // batch
            int t = row & 2047;
            if (mat == 2) {
                u16x4 pv;
                #pragma unroll
                for (int r = 0; r < 4; ++r) pv[r] = f2bf(acc[mi][ni][r] + bb);
                *(u16x4*)(vtws + ((bidx * 16 + h) * 64 + hd) * 2048 + t) = pv;
            } else {
                unsigned short* dst =
                    ((mat == 0) ? qws : kws) + ((bidx * 16 + h) * 2048 + t) * 64 + hd;
                #pragma unroll
                for (int r = 0; r < 4; ++r) dst[r * 64] = f2bf(acc[mi][ni][r] + bb);
            }
        }
    }
}

// ---------------------------------------------------------------------------
// Kernel 4: causal flash attention — swapped-operand 32x32 structure.
// (unchanged from round 2)
// ---------------------------------------------------------------------------
#define AQB 128
#define AKV 64

__global__ __launch_bounds__(256, 3) void attn_kernel(
        const unsigned short* __restrict__ qws,
        const unsigned short* __restrict__ kws,
        const unsigned short* __restrict__ vtws,
        unsigned short* __restrict__ ctx) {
    __shared__ unsigned short Ks[2][AKV * 64];   // [kv][d] swizzled, dbuf
    __shared__ unsigned short Vs[2][64 * AKV];   // [d][kv] swizzled, dbuf
    __shared__ unsigned short Os[4][32 * 64];    // per-wave O transpose buffer

    const int tid = threadIdx.x;
    const int lane = tid & 63, wid = tid >> 6;
    const int l31 = lane & 31, hi = lane >> 5;
    const int qb = 15 - (int)(blockIdx.x >> 6);   // LPT: heavy blocks first
    const int bh = blockIdx.x & 63;
    const int qbase = qb * AQB;
    const int qwbase = qbase + wid * 32;
    const unsigned short* qp = qws + bh * 2048 * 64;
    const unsigned short* kp = kws + bh * 2048 * 64;
    const unsigned short* vp = vtws + bh * 64 * 2048;

    // Q as B-operand frags; fold 1/sqrt(64) * log2(e) (exp2-domain softmax)
    const float QSCALE = 0.125f * 1.44269504f;
    bf16x8 qf[4];
    #pragma unroll
    for (int ks = 0; ks < 4; ++ks) {
        u16x8 v = *(const u16x8*)(qp + (qwbase + l31) * 64 + ks * 16 + hi * 8);
        u16x8 o;
        #pragma unroll
        for (int e = 0; e < 8; ++e) o[e] = f2bf(bf2f(v[e]) * QSCALE);
        qf[ks] = as_bf(o);
    }

    f32x16 acc0 = {}, acc1 = {};
    float m_run = -1e30f, lsum = 0.f;

    const int nt = 2 * qb + 2;                    // KV tiles for this block
    const int wnt = 2 * qb + 1 + (wid >> 1);      // tiles this wave computes

    u16x8 kr[2], vr[2];
    // prologue: stage tile 0 into buffer 0
    #pragma unroll
    for (int it = 0; it < 2; ++it) {
        int flat = it * 256 + tid, r = flat >> 3, g = flat & 7;
        kr[it] = *(const u16x8*)(kp + r * 64 + g * 8);
        vr[it] = *(const u16x8*)(vp + r * 2048 + g * 8);
    }
    #pragma unroll
    for (int it = 0; it < 2; ++it) {
        int flat = it * 256 + tid, r = flat >> 3, g = flat & 7;
        *(u16x8*)(&Ks[0][r * 64 + ((g ^ (r & 7)) << 3)]) = kr[it];
        *(u16x8*)(&Vs[0][r * 64 + ((g ^ (r & 7)) << 3)]) = vr[it];
    }
    __syncthreads();

    for (int t = 0; t < nt; ++t) {
        const int cur = t & 1;
        const int kt = t * AKV;
        // T14: issue next tile's global loads before compute
        if (t + 1 < nt) {
            int kt2 = kt + AKV;
            #pragma unroll
            for (int it = 0; it < 2; ++it) {
                int flat = it * 256 + tid, r = flat >> 3, g = flat & 7;
                kr[it] = *(const u16x8*)(kp + (kt2 + r) * 64 + g * 8);
                vr[it] = *(const u16x8*)(vp + r * 2048 + kt2 + g * 8);
            }
        }
        if (t < wnt) {
            const unsigned short* kb = &Ks[cur][0];
            const unsigned short* vb = &Vs[cur][0];
            #pragma unroll
            for (int half = 0; half < 2; ++half) {
                const int kvbase = kt + half * 32;
                if (kvbase > qwbase + 31) continue;          // fully masked
                // S^T = K @ Q  (32 kv x 32 q), 4 k-steps over d=64
                f32x16 st = {};
                #pragma unroll
                for (int ks = 0; ks < 4; ++ks) {
                    int row = half * 32 + l31;
                    int g = (ks * 2 + hi) ^ (row & 7);
                    bf16x8 kf = as_bf(*(const u16x8*)(kb + row * 64 + (g << 3)));
                    st = __builtin_amdgcn_mfma_f32_32x32x16_bf16(kf, qf[ks], st, 0, 0, 0);
                }
                // causal mask (diagonal tiles only)
                if (kvbase + 31 > qwbase) {
                    int q = qwbase + l31;
                    #pragma unroll
                    for (int r = 0; r < 16; ++r) {
                        int kv = kvbase + (r & 3) + 8 * (r >> 2) + 4 * hi;
                        if (kv > q) st[r] = -1e30f;
                    }
                }
                // row max: 15 fmax + one cross-half exchange
                float pmax = st[0];
                #pragma unroll
                for (int r = 1; r < 16; ++r) pmax = fmaxf(pmax, st[r]);
                pmax = fmaxf(pmax, __shfl_xor(pmax, 32));
                // defer-max (T13): rescale only when max grows > 11.5 (log2)
                if (!__all(pmax - m_run <= 11.5f)) {
                    float mnew = fmaxf(m_run, pmax);
                    float alpha = __builtin_amdgcn_exp2f(m_run - mnew);
                    m_run = mnew;
                    lsum *= alpha;
                    #pragma unroll
                    for (int r = 0; r < 16; ++r) { acc0[r] *= alpha; acc1[r] *= alpha; }
                }
                float p[16];
                float ls = 0.f;
                #pragma unroll
                for (int r = 0; r < 16; ++r) {
                    p[r] = __builtin_amdgcn_exp2f(st[r] - m_run);
                    ls += p[r];
                }
                lsum += ls;
                // P -> bf16 B-frags in-register (pack + cross-half shfl)
                unsigned c[8], x[8];
                #pragma unroll
                for (int i = 0; i < 8; ++i) c[i] = packbf(p[2 * i], p[2 * i + 1]);
                #pragma unroll
                for (int i = 0; i < 8; ++i) x[i] = (unsigned)__shfl_xor((int)c[i], 32);
                union { u16x8 v; unsigned w[4]; } pb0, pb1;
                pb0.w[0] = hi ? x[2] : c[0];
                pb0.w[1] = hi ? x[3] : c[1];
                pb0.w[2] = hi ? c[2] : x[0];
                pb0.w[3] = hi ? c[3] : x[1];
                pb1.w[0] = hi ? x[6] : c[4];
                pb1.w[1] = hi ? x[7] : c[5];
                pb1.w[2] = hi ? c[6] : x[4];
                pb1.w[3] = hi ? c[7] : x[5];
                // O^T += V^T @ P^T   (2 d-blocks x 2 k-steps)
                #pragma unroll
                for (int db = 0; db < 2; ++db) {
                    f32x16& accd = db ? acc1 : acc0;
                    #pragma unroll
                    for (int ks2 = 0; ks2 < 2; ++ks2) {
                        int row = db * 32 + l31;
                        int g = (half * 4 + ks2 * 2 + hi) ^ (row & 7);
                        bf16x8 vf = as_bf(*(const u16x8*)(vb + row * 64 + (g << 3)));
                        accd = __builtin_amdgcn_mfma_f32_32x32x16_bf16(
                            vf, ks2 ? pb1.v : pb0.v, accd, 0, 0, 0);
                    }
                }
            }
        }
        __syncthreads();
        if (t + 1 < nt) {
            unsigned short* dk = &Ks[cur ^ 1][0];
            unsigned short* dv = &Vs[cur ^ 1][0];
            #pragma unroll
            for (int it = 0; it < 2; ++it) {
                int flat = it * 256 + tid, r = flat >> 3, g = flat & 7;
                *(u16x8*)(dk + r * 64 + ((g ^ (r & 7)) << 3)) = kr[it];
                *(u16x8*)(dv + r * 64 + ((g ^ (r & 7)) << 3)) = vr[it];
            }
        }
        __syncthreads();
    }

    // epilogue: combine halves, normalize, transpose via LDS, coalesced store
    lsum += __shfl_xor(lsum, 32);
    float rinv = __builtin_amdgcn_rcpf(lsum);
    unsigned short* ow = &Os[wid][0];
    #pragma unroll
    for (int db = 0; db < 2; ++db) {
        const f32x16& accd = db ? acc1 : acc0;
        #pragma unroll
        for (int r = 0; r < 16; r += 2) {
            int d = db * 32 + (r & 3) + 8 * (r >> 2) + 4 * hi;
            unsigned w = packbf(accd[r] * rinv, accd[r + 1] * rinv);
            int g = (d >> 3) ^ (l31 & 7);
            *(unsigned*)(ow + l31 * 64 + (g << 3) + (d & 7)) = w;
        }
    }
    __syncthreads();
    const int bidx = bh >> 4, h = bh & 15;
    #pragma unroll
    for (int rr = 0; rr < 4; ++rr) {
        int flat = rr * 64 + lane;                 // 0..255
        int q = flat >> 3, g = flat & 7;
        u16x8 v = *(const u16x8*)(ow + q * 64 + ((g ^ (q & 7)) << 3));
        int qg = qbase + wid * 32 + q;
        *(u16x8*)(ctx + (bidx * 2048 + qg) * 1024 + h * 64 + g * 8) = v;
    }
}

// ---------------------------------------------------------------------------
// Kernel 5: output GEMM. out[8192,1024] f32 = ctx[8192,1024] @ Wo + bo
// Same global_load_lds staging as kernel 3.
// ---------------------------------------------------------------------------
__global__ __launch_bounds__(256) void out_gemm_kernel(
        const unsigned short* __restrict__ ctx,
        const unsigned short* __restrict__ wot,
        const float* __restrict__ bo,
        float* __restrict__ out) {
    __shared__ unsigned short As[BM * BK];
    __shared__ unsigned short Bs[BN * BK];
    const int tid = threadIdx.x;
    const int lane = tid & 63, wid = tid >> 6;
    const int wr = wid >> 1, wc = wid & 1;
    const int l15 = lane & 15, lg = lane >> 4;
    const int mbase = blockIdx.y * BM;
    const int nbase = blockIdx.x * BN;

    const int rsub = lane >> 3;
    const int gsw  = (lane & 7) ^ rsub;
    const unsigned short* asrc0 = ctx + (mbase + wid * 32 + rsub) * 1024 + gsw * 8;
    const unsigned short* bsrc0 = wot + (nbase + wid * 32 + rsub) * 1024 + gsw * 8;
    char* adst0 = (char*)As + wid * 4096;
    char* bdst0 = (char*)Bs + wid * 4096;

    f32x4 acc[4][4] = {};

    for (int k0 = 0; k0 < 1024; k0 += BK) {
        __syncthreads();
        #pragma unroll
        for (int i = 0; i < 4; ++i)
            gload_lds16(asrc0 + i * 8 * 1024 + k0, adst0 + i * 1024);
        #pragma unroll
        for (int i = 0; i < 4; ++i)
            gload_lds16(bsrc0 + i * 8 * 1024 + k0, bdst0 + i * 1024);
        __syncthreads();
        #pragma unroll
        for (int kk = 0; kk < 2; ++kk) {
            bf16x8 a[4], b[4];
            #pragma unroll
            for (int mi = 0; mi < 4; ++mi) {
                int m = wr * 64 + mi * 16 + l15;
                int g = (kk * 4 + lg) ^ (m & 7);
                a[mi] = as_bf(*(const u16x8*)(As + m * 64 + (g << 3)));
            }
            #pragma unroll
            for (int ni = 0; ni < 4; ++ni) {
                int n = wc * 64 + ni * 16 + l15;
                int g = (kk * 4 + lg) ^ (n & 7);
                b[ni] = as_bf(*(const u16x8*)(Bs + n * 64 + (g << 3)));
            }
            #pragma unroll
            for (int mi = 0; mi < 4; ++mi)
                #pragma unroll
                for (int ni = 0; ni < 4; ++ni)
                    acc[mi][ni] = __builtin_amdgcn_mfma_f32_16x16x32_bf16(
                        a[mi], b[ni], acc[mi][ni], 0, 0, 0);
        }
    }

    #pragma unroll
    for (int ni = 0; ni < 4; ++ni) {
        int ncol = nbase + wc * 64 + ni * 16 + l15;
        float bb = bo[ncol];
        #pragma unroll
        for (int mi = 0; mi < 4; ++mi) {
            int row = mbase + wr * 64 + mi * 16 + lg * 4;
            #pragma unroll
            for (int r = 0; r < 4; ++r)
                out[(row + r) * 1024 + ncol] = acc[mi][ni][r] + bb;
        }
    }
}

// ---------------------------------------------------------------------------
extern "C" void kernel_launch(void* const* d_in, const int* in_sizes, int n_in,
                              void* d_out, int out_size, void* d_ws, size_t ws_size,
                              hipStream_t stream) {
    const float* x  = (const float*)d_in[0];
    const float* wq = (const float*)d_in[1];
    const float* bq = (const float*)d_in[2];
    const float* wk = (const float*)d_in[3];
    const float* bk = (const float*)d_in[4];
    const float* wv = (const float*)d_in[5];
    const float* bv = (const float*)d_in[6];
    const float* wo = (const float*)d_in[7];
    const float* bo = (const float*)d_in[8];
    float* out = (float*)d_out;

    char* ws = (char*)d_ws;
    unsigned short* xb   = (unsigned short*)(ws);                         // 16 MB
    unsigned short* wqt  = (unsigned short*)(ws + (16u << 20));           // 2 MB
    unsigned short* wkt  = (unsigned short*)(ws + (18u << 20));           // 2 MB
    unsigned short* wvt  = (unsigned short*)(ws + (20u << 20));           // 2 MB
    unsigned short* wot  = (unsigned short*)(ws + (22u << 20));           // 2 MB
    unsigned short* qws  = (unsigned short*)(ws + (24u << 20));           // 16 MB
    unsigned short* kws  = (unsigned short*)(ws + (40u << 20));           // 16 MB
    unsigned short* vtws = (unsigned short*)(ws + (56u << 20));           // 16 MB
    unsigned short* ctx  = (unsigned short*)(ws + (72u << 20));           // 16 MB

    cvt_x_kernel<<<4096, 256, 0, stream>>>(x, xb);
    cvt_w_t_kernel<<<dim3(32, 32, 4), 256, 0, stream>>>(wq, wk, wv, wo,
                                                        wqt, wkt, wvt, wot);
    qkv_gemm_kernel<<<dim3(24, 64), 256, 0, stream>>>(xb, wqt, bq, bk, bv,
                                                      qws, kws, vtws);
    attn_kernel<<<1024, 256, 0, stream>>>(qws, kws, vtws, ctx);
    out_gemm_kernel<<<dim3(8, 64), 256, 0, stream>>>(ctx, wot, bo, out);
}